// Round 12
// baseline (545.961 us; speedup 1.0000x reference)
//
#include <hip/hip_runtime.h>

typedef unsigned long long u64;
typedef float f32x4 __attribute__((ext_vector_type(4)));

#define THR 0.5f

__device__ __forceinline__ u64 rdl64c(u64 v, int l) {  // constant/uniform lane
  unsigned lo = (unsigned)__builtin_amdgcn_readlane((int)(unsigned)v, l);
  unsigned hi = (unsigned)__builtin_amdgcn_readlane((int)(unsigned)(v >> 32), l);
  return ((u64)hi << 32) | lo;
}

// Convert one cxcywh box to ltrb + area, FP contraction OFF (bit-exact vs numpy
// for the NMS >= 0.5 predicate).
__device__ __forceinline__ void conv_box(const float4 b, float& l, float& t,
                                         float& r, float& bo, float& a) {
  #pragma clang fp contract(off)
  float hw = 0.5f * b.z;
  float hh = 0.5f * b.w;
  l = b.x - hw;
  t = b.y - hh;
  r = b.x + hw;
  bo = b.y + hh;
  a = (r - l) * (bo - t);
}

__global__ void k_zero(int* __restrict__ rank, int n) {
  int i = blockIdx.x * blockDim.x + threadIdx.x;
  if (i < n) rank[i] = 0;
}

__global__ void k_rank(const float* __restrict__ scores, int* __restrict__ rank,
                       int n, int jchunk) {
  int i = blockIdx.x * blockDim.x + threadIdx.x;
  if (i >= n) return;
  float si = scores[i];
  int j0 = blockIdx.y * jchunk;
  int j1 = min(j0 + jchunk, n);
  int c = 0;
  for (int j = j0; j < j1; ++j) {
    float sj = scores[j];
    c += ((sj > si) || (sj == si && j < i)) ? 1 : 0;
  }
  if (c) atomicAdd(rank + i, c);
}

__global__ void k_scatter(const float4* __restrict__ boxes, const int* __restrict__ rank,
                          float* __restrict__ sl, float* __restrict__ st,
                          float* __restrict__ sr, float* __restrict__ sb,
                          float* __restrict__ sa, int* __restrict__ sidx, int n) {
  int i = blockIdx.x * blockDim.x + threadIdx.x;
  if (i >= n) return;
  float l, t, r, b, a;
  conv_box(boxes[i], l, t, r, b, a);
  int k = rank[i];
  sl[k] = l; st[k] = t; sr[k] = r; sb[k] = b; sa[k] = a; sidx[k] = i;
}

// mask[k][w] bit b (j=w*64+b) set iff j>k, j<n, iou_nms(k,j) >= 0.5.
// Emits diag + band1/band2 (superdiagonal words). No clamp on inter (matches
// the reference NMS path exactly).
__device__ __forceinline__ void mask_body(
    const float* __restrict__ sl, const float* __restrict__ st,
    const float* __restrict__ sr, const float* __restrict__ sb,
    const float* __restrict__ sa,
    u64* __restrict__ mask, u64* __restrict__ diag,
    u64* __restrict__ band1, u64* __restrict__ band2,
    int n, int wstride, int bx, int by) {
  #pragma clang fp contract(off)
  int k = bx * 256 + threadIdx.x;
  if (k >= n) return;
  int w = by;
  int jbase = w << 6;
  u64 word = 0;
  if (jbase + 63 > k) {
    float l = sl[k], t = st[k], r = sr[k], b = sb[k], a = sa[k];
    int jend = min(jbase + 64, n);
    for (int j = max(jbase, k + 1); j < jend; ++j) {
      float lmax = fmaxf(l, sl[j]);
      float tmax = fmaxf(t, st[j]);
      float rmin = fminf(r, sr[j]);
      float bmin = fminf(b, sb[j]);
      float wd = rmin - lmax;
      float hd = bmin - tmax;
      float inter = wd * hd;
      float denom = (a + sa[j]) - inter;
      float q = inter / denom;
      if (q >= THR) word |= 1ull << (j - jbase);
    }
  }
  mask[(size_t)k * wstride + w] = word;
  int kg = k >> 6;
  if (kg == w) diag[k] = word;
  if (w == kg + 1) band1[k] = word;
  if (w == kg + 2) band2[k] = word;
}

__global__ void k_mask(const float* __restrict__ sl, const float* __restrict__ st,
                       const float* __restrict__ sr, const float* __restrict__ sb,
                       const float* __restrict__ sa,
                       u64* __restrict__ mask, u64* __restrict__ diag,
                       u64* __restrict__ band1, u64* __restrict__ band2,
                       int n, int wstride) {
  mask_body(sl, st, sr, sb, sa, mask, diag, band1, band2, n, wstride,
            blockIdx.x, blockIdx.y);
}

// wave64 OR-reduce via DPP; result uniform.
__device__ __forceinline__ u64 wave_or_u64(u64 v) {
  unsigned lo = (unsigned)v, hi = (unsigned)(v >> 32);
#define DPP_OR(x, ctrl, rmask) \
  x |= (unsigned)__builtin_amdgcn_update_dpp(0, (int)(x), ctrl, rmask, 0xF, true)
  DPP_OR(lo, 0x111, 0xF); DPP_OR(hi, 0x111, 0xF);
  DPP_OR(lo, 0x112, 0xF); DPP_OR(hi, 0x112, 0xF);
  DPP_OR(lo, 0x114, 0xF); DPP_OR(hi, 0x114, 0xF);
  DPP_OR(lo, 0x118, 0xF); DPP_OR(hi, 0x118, 0xF);
  DPP_OR(lo, 0x142, 0xA); DPP_OR(hi, 0x142, 0xA);
  DPP_OR(lo, 0x143, 0xC); DPP_OR(hi, 0x143, 0xC);
#undef DPP_OR
  unsigned flo = (unsigned)__builtin_amdgcn_readlane((int)lo, 63);
  unsigned fhi = (unsigned)__builtin_amdgcn_readlane((int)hi, 63);
  return ((u64)fhi << 32) | flo;
}

// Immediate fold of up to 8 kept rows (overflow path, early groups only).
__device__ __forceinline__ void fold8_now(const u64* __restrict__ mask, int base,
    u64 bits, int cnt, int wstride, int lane, int w2c,
    u64& r0, u64& r1, u64& r2) {
  u64 t = bits;
  int k0 = __ffsll((long long)t) - 1; t &= t - 1;
  int k1 = __ffsll((long long)t) - 1; t &= t - 1;
  int k2 = __ffsll((long long)t) - 1; t &= t - 1;
  int k3 = __ffsll((long long)t) - 1; t &= t - 1;
  int k4 = __ffsll((long long)t) - 1; t &= t - 1;
  int k5 = __ffsll((long long)t) - 1; t &= t - 1;
  int k6 = __ffsll((long long)t) - 1; t &= t - 1;
  int k7 = __ffsll((long long)t) - 1;
  k0 = max(k0, 0); k1 = max(k1, 0); k2 = max(k2, 0); k3 = max(k3, 0);
  k4 = max(k4, 0); k5 = max(k5, 0); k6 = max(k6, 0); k7 = max(k7, 0);
  const u64* p0 = mask + (size_t)(base + k0) * wstride;
  const u64* p1 = mask + (size_t)(base + k1) * wstride;
  const u64* p2 = mask + (size_t)(base + k2) * wstride;
  const u64* p3 = mask + (size_t)(base + k3) * wstride;
  const u64* p4 = mask + (size_t)(base + k4) * wstride;
  const u64* p5 = mask + (size_t)(base + k5) * wstride;
  const u64* p6 = mask + (size_t)(base + k6) * wstride;
  const u64* p7 = mask + (size_t)(base + k7) * wstride;
  u64 a0=p0[lane], a1=p0[lane+64], a2=p0[w2c];
  u64 b0=p1[lane], b1=p1[lane+64], b2=p1[w2c];
  u64 c0=p2[lane], c1=p2[lane+64], c2=p2[w2c];
  u64 d0=p3[lane], d1=p3[lane+64], d2=p3[w2c];
  u64 e0=p4[lane], e1=p4[lane+64], e2=p4[w2c];
  u64 f0=p5[lane], f1=p5[lane+64], f2=p5[w2c];
  u64 g0=p6[lane], g1=p6[lane+64], g2=p6[w2c];
  u64 h0=p7[lane], h1=p7[lane+64], h2=p7[w2c];
  if (cnt > 0) { r0|=a0; r1|=a1; r2|=a2; }
  if (cnt > 1) { r0|=b0; r1|=b1; r2|=b2; }
  if (cnt > 2) { r0|=c0; r1|=c1; r2|=c2; }
  if (cnt > 3) { r0|=d0; r1|=d1; r2|=d2; }
  if (cnt > 4) { r0|=e0; r1|=e1; r2|=e2; }
  if (cnt > 5) { r0|=f0; r1|=f1; r2|=f2; }
  if (cnt > 6) { r0|=g0; r1|=g1; r2|=g2; }
  if (cnt > 7) { r0|=h0; r1|=h1; r2|=h2; }
}

// ---------------------------------------------------------------------------
// Greedy serial NMS scan — ONE wave, ZERO barriers, ZERO LDS (round-11 lesson:
// 4-wave coordination put 157 barriers + LDS/SMEM drains on the serial path).
//  * rem in per-lane regs r0/r1/r2; seed = one v_readlane (dynamic index).
//  * diag per-lane in d_cur (depth-2 vector prefetch); chain step b sources
//    its word via constant-index readlane -> pure SALU cselect chain.
//  * distance 1-2 via R1/R2 DPP band; fold (first 8 kept rows) issued into
//    NAMED reg buffers at group g, OR'd in at g+2 (one group of latency
//    slack); overflow rows (early groups) pay immediate latency.
// ---------------------------------------------------------------------------
__global__ __launch_bounds__(64, 1) void k_scan3(
    const u64* __restrict__ mask, const u64* __restrict__ diag,
    const u64* __restrict__ band1, const u64* __restrict__ band2,
    const int* __restrict__ sidx, float* __restrict__ keep,
    int n, int wstride) {
  int lane = threadIdx.x;
  int ng = (n + 63) >> 6;
  int words = ng;
  int w2c = min(lane + 128, words - 1);
  u64 r0 = 0, r1 = 0, r2 = 0;
  u64 R1 = 0, R2 = 0;
  u64 d_cur = diag[lane],  d_nx = diag[64 + lane];
  u64 b1_cur = band1[lane], b1_nx = band1[64 + lane];
  u64 b2_cur = band2[lane], b2_nx = band2[64 + lane];
  int sx_cur = (lane < n) ? sidx[lane] : 0;
  int sx_nx  = (64 + lane < n) ? sidx[64 + lane] : 0;
  // fold double buffers: 8 rows x 3 words, by group parity
  u64 fA00=0,fA01=0,fA02=0,fA10=0,fA11=0,fA12=0,fA20=0,fA21=0,fA22=0,
      fA30=0,fA31=0,fA32=0,fA40=0,fA41=0,fA42=0,fA50=0,fA51=0,fA52=0,
      fA60=0,fA61=0,fA62=0,fA70=0,fA71=0,fA72=0;
  u64 fB00=0,fB01=0,fB02=0,fB10=0,fB11=0,fB12=0,fB20=0,fB21=0,fB22=0,
      fB30=0,fB31=0,fB32=0,fB40=0,fB41=0,fB42=0,fB50=0,fB51=0,fB52=0,
      fB60=0,fB61=0,fB62=0,fB70=0,fB71=0,fB72=0;
  int nkA = 0, nkB = 0;

  for (int g = 0; g < ng; ++g) {
    int base = g << 6;
    // 1) drain fold buffer filled at g-2 (same parity)
    if ((g & 1) == 0) {
      if (nkA > 0) { r0|=fA00; r1|=fA01; r2|=fA02; }
      if (nkA > 1) { r0|=fA10; r1|=fA11; r2|=fA12; }
      if (nkA > 2) { r0|=fA20; r1|=fA21; r2|=fA22; }
      if (nkA > 3) { r0|=fA30; r1|=fA31; r2|=fA32; }
      if (nkA > 4) { r0|=fA40; r1|=fA41; r2|=fA42; }
      if (nkA > 5) { r0|=fA50; r1|=fA51; r2|=fA52; }
      if (nkA > 6) { r0|=fA60; r1|=fA61; r2|=fA62; }
      if (nkA > 7) { r0|=fA70; r1|=fA71; r2|=fA72; }
      nkA = 0;
    } else {
      if (nkB > 0) { r0|=fB00; r1|=fB01; r2|=fB02; }
      if (nkB > 1) { r0|=fB10; r1|=fB11; r2|=fB12; }
      if (nkB > 2) { r0|=fB20; r1|=fB21; r2|=fB22; }
      if (nkB > 3) { r0|=fB30; r1|=fB31; r2|=fB32; }
      if (nkB > 4) { r0|=fB40; r1|=fB41; r2|=fB42; }
      if (nkB > 5) { r0|=fB50; r1|=fB51; r2|=fB52; }
      if (nkB > 6) { r0|=fB60; r1|=fB61; r2|=fB62; }
      if (nkB > 7) { r0|=fB70; r1|=fB71; r2|=fB72; }
      nkB = 0;
    }
    // 2) seed: rem[g] via readlane + band regs
    u64 rr = (g < 64) ? r0 : (g < 128) ? r1 : r2;
    u64 s = rdl64c(rr, g & 63) | R1;
    int valid = n - base;
    if (valid < 64) s |= (~0ull) << valid;
    // 3) serial chain: SALU, EQ words via constant-index readlane on d_cur
    u64 kw = 0;
#define SSTEP(BB, EQ) { u64 sup = (s >> (BB)) & 1ull; \
    kw |= (sup ^ 1ull) << (BB); s |= sup ? 0ull : (EQ); }
#define SCHUNK(B0v) \
    if (((~s >> (B0v)) & 0xFFull) != 0ull) { \
      u64 E0 = rdl64c(d_cur, (B0v)+0); u64 E1 = rdl64c(d_cur, (B0v)+1); \
      u64 E2 = rdl64c(d_cur, (B0v)+2); u64 E3 = rdl64c(d_cur, (B0v)+3); \
      u64 E4 = rdl64c(d_cur, (B0v)+4); u64 E5 = rdl64c(d_cur, (B0v)+5); \
      u64 E6 = rdl64c(d_cur, (B0v)+6); u64 E7 = rdl64c(d_cur, (B0v)+7); \
      SSTEP((B0v)+0, E0) SSTEP((B0v)+1, E1) SSTEP((B0v)+2, E2) SSTEP((B0v)+3, E3) \
      SSTEP((B0v)+4, E4) SSTEP((B0v)+5, E5) SSTEP((B0v)+6, E6) SSTEP((B0v)+7, E7) }
    SCHUNK(0) SCHUNK(8) SCHUNK(16) SCHUNK(24)
    SCHUNK(32) SCHUNK(40) SCHUNK(48) SCHUNK(56)
#undef SCHUNK
#undef SSTEP
    // 4) keep scatter (store, off-path)
    if (base + lane < n) keep[sx_cur] = ((kw >> lane) & 1ull) ? 1.0f : 0.0f;
    // 5) band words for g+1/g+2 via DPP reduce
    u64 m = (u64)0 - ((kw >> lane) & 1ull);
    u64 c1 = wave_or_u64(b1_cur & m);
    u64 c2 = wave_or_u64(b2_cur & m);
    R1 = R2 | c1;
    R2 = c2;
    // 6) fold: first 8 kept rows -> deferred reg buffer (drained at g+2)
    int nk = __popcll(kw);
    if (nk > 0) {
      u64 t = kw;
      int kk0 = __ffsll((long long)t) - 1; t &= t - 1;
      int kk1 = __ffsll((long long)t) - 1; t &= t - 1;
      int kk2 = __ffsll((long long)t) - 1; t &= t - 1;
      int kk3 = __ffsll((long long)t) - 1; t &= t - 1;
      int kk4 = __ffsll((long long)t) - 1; t &= t - 1;
      int kk5 = __ffsll((long long)t) - 1; t &= t - 1;
      int kk6 = __ffsll((long long)t) - 1; t &= t - 1;
      int kk7 = __ffsll((long long)t) - 1; t &= t - 1;
      kk0 = max(kk0,0); kk1 = max(kk1,0); kk2 = max(kk2,0); kk3 = max(kk3,0);
      kk4 = max(kk4,0); kk5 = max(kk5,0); kk6 = max(kk6,0); kk7 = max(kk7,0);
      const u64* p0 = mask + (size_t)(base + kk0) * wstride;
      const u64* p1 = mask + (size_t)(base + kk1) * wstride;
      const u64* p2 = mask + (size_t)(base + kk2) * wstride;
      const u64* p3 = mask + (size_t)(base + kk3) * wstride;
      const u64* p4 = mask + (size_t)(base + kk4) * wstride;
      const u64* p5 = mask + (size_t)(base + kk5) * wstride;
      const u64* p6 = mask + (size_t)(base + kk6) * wstride;
      const u64* p7 = mask + (size_t)(base + kk7) * wstride;
      if ((g & 1) == 0) {
        fA00=p0[lane]; fA01=p0[lane+64]; fA02=p0[w2c];
        fA10=p1[lane]; fA11=p1[lane+64]; fA12=p1[w2c];
        fA20=p2[lane]; fA21=p2[lane+64]; fA22=p2[w2c];
        fA30=p3[lane]; fA31=p3[lane+64]; fA32=p3[w2c];
        fA40=p4[lane]; fA41=p4[lane+64]; fA42=p4[w2c];
        fA50=p5[lane]; fA51=p5[lane+64]; fA52=p5[w2c];
        fA60=p6[lane]; fA61=p6[lane+64]; fA62=p6[w2c];
        fA70=p7[lane]; fA71=p7[lane+64]; fA72=p7[w2c];
        nkA = min(nk, 8);
      } else {
        fB00=p0[lane]; fB01=p0[lane+64]; fB02=p0[w2c];
        fB10=p1[lane]; fB11=p1[lane+64]; fB12=p1[w2c];
        fB20=p2[lane]; fB21=p2[lane+64]; fB22=p2[w2c];
        fB30=p3[lane]; fB31=p3[lane+64]; fB32=p3[w2c];
        fB40=p4[lane]; fB41=p4[lane+64]; fB42=p4[w2c];
        fB50=p5[lane]; fB51=p5[lane+64]; fB52=p5[w2c];
        fB60=p6[lane]; fB61=p6[lane+64]; fB62=p6[w2c];
        fB70=p7[lane]; fB71=p7[lane+64]; fB72=p7[w2c];
        nkB = min(nk, 8);
      }
      // overflow rows: immediate fold (early, dense groups only)
      int remn = nk - 8;
      while (remn > 0) {
        fold8_now(mask, base, t, remn, wstride, lane, w2c, r0, r1, r2);
        #pragma unroll
        for (int j = 0; j < 8; ++j) t &= t - 1;
        remn -= 8;
      }
    } else {
      if ((g & 1) == 0) nkA = 0; else nkB = 0;
    }
    // 7) rotate depth-2 prefetch streams (arrays padded +128)
    d_cur = d_nx;   d_nx  = diag[base + 128 + lane];
    b1_cur = b1_nx; b1_nx = band1[base + 128 + lane];
    b2_cur = b2_nx; b2_nx = band2[base + 128 + lane];
    sx_cur = sx_nx;
    int nxt2 = base + 128 + lane;
    sx_nx = (nxt2 < n) ? sidx[nxt2] : 0;
  }
}

// Pairwise IoU, original order, WITH clamp. Loose 2e-2 threshold -> fast rcp.
__device__ __forceinline__ float iou_one(float li, float ti, float ri, float bi, float ai,
                                         float lj, float tj, float rj, float bj, float aj) {
  float lmax = fmaxf(li, lj);
  float tmax = fmaxf(ti, tj);
  float rmin = fminf(ri, rj);
  float bmin = fminf(bi, bj);
  float w = fmaxf(rmin - lmax, 0.0f);
  float h = fmaxf(bmin - tmax, 0.0f);
  float inter = w * h;
  float denom = (ai + aj) - inter;
  return inter * __builtin_amdgcn_rcpf(denom);
}

__device__ __forceinline__ void iou_body(const float4* __restrict__ boxes,
                                         float* __restrict__ out,
                                         int n, int rpb, int bx, int by) {
  int nj4 = (n + 3) >> 2;
  int j4 = bx * 256 + threadIdx.x;
  if (j4 >= nj4) return;
  int j = j4 << 2;
  int jc1 = min(j + 1, n - 1), jc2 = min(j + 2, n - 1), jc3 = min(j + 3, n - 1);
  float l0,t0,r0,b0,a0, l1,t1,r1,b1,a1, l2,t2,r2,b2,a2, l3,t3,r3,b3,a3;
  conv_box(boxes[j],   l0,t0,r0,b0,a0);
  conv_box(boxes[jc1], l1,t1,r1,b1,a1);
  conv_box(boxes[jc2], l2,t2,r2,b2,a2);
  conv_box(boxes[jc3], l3,t3,r3,b3,a3);
  bool full = (j + 3) < n;
  for (int rr = 0; rr < rpb; ++rr) {
    int i = by * rpb + rr;
    if (i >= n) return;
    float li,ti,ri,bi,ai;
    conv_box(boxes[i], li,ti,ri,bi,ai);
    float4 o;
    o.x = iou_one(li,ti,ri,bi,ai, l0,t0,r0,b0,a0);
    o.y = iou_one(li,ti,ri,bi,ai, l1,t1,r1,b1,a1);
    o.z = iou_one(li,ti,ri,bi,ai, l2,t2,r2,b2,a2);
    o.w = iou_one(li,ti,ri,bi,ai, l3,t3,r3,b3,a3);
    size_t row = (size_t)i * n;
    if (full) {
      f32x4 ov = { o.x, o.y, o.z, o.w };
      __builtin_nontemporal_store(ov, reinterpret_cast<f32x4*>(out + row + j));
    } else {
      out[row + j] = o.x;
      if (j + 1 < n) out[row + j + 1] = o.y;
      if (j + 2 < n) out[row + j + 2] = o.z;
    }
  }
}

__global__ void k_iou(const float4* __restrict__ boxes, float* __restrict__ out,
                      int n, int rpb) {
  iou_body(boxes, out, n, rpb, blockIdx.x, blockIdx.y);
}

// Fused mask + IoU (independent work, disjoint outputs).
__global__ __launch_bounds__(256) void k_maskiou(
    const float* __restrict__ sl, const float* __restrict__ st,
    const float* __restrict__ sr, const float* __restrict__ sb,
    const float* __restrict__ sa,
    u64* __restrict__ mask, u64* __restrict__ diag,
    u64* __restrict__ band1, u64* __restrict__ band2,
    int wstride, const float4* __restrict__ boxes, float* __restrict__ out,
    int n, int rpb, int nbx, int nmask, int gx) {
  int id = blockIdx.x;
  if (id < nmask) {
    mask_body(sl, st, sr, sb, sa, mask, diag, band1, band2, n, wstride,
              id % nbx, id / nbx);
  } else {
    int iid = id - nmask;
    iou_body(boxes, out, n, rpb, iid % gx, iid / gx);
  }
}

extern "C" void kernel_launch(void* const* d_in, const int* in_sizes, int n_in,
                              void* d_out, int out_size, void* d_ws, size_t ws_size,
                              hipStream_t stream) {
  const float* boxes = (const float*)d_in[0];
  const float* scores = (const float*)d_in[1];
  int n = in_sizes[1];
  float* out = (float*)d_out;
  size_t NN = (size_t)n * (size_t)n;
  float* keep = out + NN;

  int words = (n + 63) >> 6;
  int wstride = (words + 3) & ~3;
  size_t dbsz = (size_t)words * 64 + 128;        // diag/band padded +128 (prefetch)
  size_t need = (size_t)n * wstride * 8
              + dbsz * 8 * 3
              + 256
              + (size_t)n * 4 * 7;
  bool use_ws = (ws_size >= need);

  char* base = use_ws ? (char*)d_ws : (char*)d_out;
  size_t off = 0;
  u64* mask  = (u64*)(base + off); off += (size_t)n * wstride * 8;
  u64* diag  = (u64*)(base + off); off += dbsz * 8;
  u64* band1 = (u64*)(base + off); off += dbsz * 8;
  u64* band2 = (u64*)(base + off); off += dbsz * 8;
  off = (off + 255) & ~(size_t)255;
  float* sl  = (float*)(base + off); off += (size_t)n * 4;
  float* st_ = (float*)(base + off); off += (size_t)n * 4;
  float* sr  = (float*)(base + off); off += (size_t)n * 4;
  float* sb  = (float*)(base + off); off += (size_t)n * 4;
  float* sa  = (float*)(base + off); off += (size_t)n * 4;
  int* sidx  = (int*)(base + off); off += (size_t)n * 4;
  int* rank  = (int*)(base + off); off += (size_t)n * 4;

  int nb = (n + 255) / 256;
  k_zero<<<nb, 256, 0, stream>>>(rank, n);

  int jblocks = 40;
  int jchunk = (n + jblocks - 1) / jblocks;
  k_rank<<<dim3(nb, jblocks), 256, 0, stream>>>(scores, rank, n, jchunk);

  k_scatter<<<nb, 256, 0, stream>>>((const float4*)boxes, rank, sl, st_, sr, sb, sa, sidx, n);

  int rpb = 10;
  int nj4 = (n + 3) >> 2;
  int gx = (nj4 + 255) / 256;
  int gy = (n + rpb - 1) / rpb;

  if (use_ws) {
    int nmask = nb * words;
    int total = nmask + gx * gy;
    k_maskiou<<<total, 256, 0, stream>>>(sl, st_, sr, sb, sa, mask, diag, band1,
                                         band2, wstride, (const float4*)boxes,
                                         out, n, rpb, nb, nmask, gx);
    k_scan3<<<1, 64, 0, stream>>>(mask, diag, band1, band2, sidx, keep, n, wstride);
  } else {
    k_mask<<<dim3(nb, words), 256, 0, stream>>>(sl, st_, sr, sb, sa, mask, diag,
                                                band1, band2, n, wstride);
    k_scan3<<<1, 64, 0, stream>>>(mask, diag, band1, band2, sidx, keep, n, wstride);
    k_iou<<<dim3(gx, gy), 256, 0, stream>>>((const float4*)boxes, out, n, rpb);
  }
}